// Round 4
// baseline (2237.874 us; speedup 1.0000x reference)
//
#include <hip/hip_runtime.h>

typedef unsigned short u16;
typedef unsigned int u32;

#define N_NODES 100000
#define IN_CH 512
#define HID_CH 256
#define CAP_E 3200000

__device__ __forceinline__ float b2f(u16 u) {
  union { u32 i; float f; } v; v.i = ((u32)u) << 16; return v.f;
}
__device__ __forceinline__ u16 f2b(float f) {
  union { float f; u32 i; } v; v.f = f;
  u32 r = v.i + 0x7fffu + ((v.i >> 16) & 1u);
  return (u16)(r >> 16);
}

struct TyBF {}; struct TyF32 {};
template<class T> struct IsF32;
template<> struct IsF32<TyBF>  { static constexpr int v = 0; };
template<> struct IsF32<TyF32> { static constexpr int v = 1; };

template<class T> __device__ __forceinline__ float ldv(const void* p, size_t i);
template<> __device__ __forceinline__ float ldv<TyBF>(const void* p, size_t i) {
  return b2f(((const u16*)p)[i]);
}
template<> __device__ __forceinline__ float ldv<TyF32>(const void* p, size_t i) {
  return ((const float*)p)[i];
}
template<class T> __device__ __forceinline__ void stv(void* p, size_t i, float v);
template<> __device__ __forceinline__ void stv<TyBF>(void* p, size_t i, float v) {
  ((u16*)p)[i] = f2b(v);
}
template<> __device__ __forceinline__ void stv<TyF32>(void* p, size_t i, float v) {
  ((float*)p)[i] = v;
}

// ---------------- runtime dtype probes ----------------
// flags[0]: 1 if float tensors are fp32, 0 if bf16
// flags[1]: 1 if edge_index is int32, 0 if int64 (read as int32 pairs)

__global__ void detect_kernel(const u32* __restrict__ xw, const int* __restrict__ ei,
                              int* __restrict__ flags) {
  __shared__ int c1, c2;
  int t = threadIdx.x;  // 256
  if (t == 0) { c1 = 0; c2 = 0; }
  __syncthreads();
  // bits 14:7 of each u32 word: bf16 buffer -> exponent of element 2t (in N(0,1)
  // band [110,135] ~always); fp32 buffer -> random mantissa bits (~10% in band).
  u32 w = xw[t];
  int e = (w >> 7) & 0xFF;
  if (e >= 110 && e <= 135) atomicAdd(&c1, 1);
  // int64 edge_index: odd 32-bit words are hi-words == 0
  if (ei[2 * t + 1] != 0) atomicAdd(&c2, 1);
  __syncthreads();
  if (t == 0) {
    flags[0] = (c1 < 154) ? 1 : 0;  // <60% in band => fp32
    flags[1] = (c2 > 0) ? 1 : 0;
  }
}

// ---------------- graph build (CSR) ----------------

__global__ void count_kernel(const int* __restrict__ ei, const int* __restrict__ flags,
                             int* __restrict__ cnt, int E) {
  int e = blockIdx.x * blockDim.x + threadIdx.x;
  if (e >= E) return;
  int s, d;
  if (flags[1]) { s = ei[e]; d = ei[E + e]; }
  else          { s = ei[2 * e]; d = ei[2 * (E + e)]; }
  if ((u32)s >= N_NODES || (u32)d >= N_NODES) return;
  atomicAdd(&cnt[d], 1);
}

// single-block exclusive scan of cnt -> offs (N entries)
__global__ __launch_bounds__(256) void scan_kernel(const int* __restrict__ cnt,
                                                   int* __restrict__ offs) {
  __shared__ int sums[256];
  __shared__ int carry;
  int t = threadIdx.x;
  if (t == 0) carry = 0;
  __syncthreads();
  const int CHUNK = 256 * 16;
  for (int base = 0; base < N_NODES; base += CHUNK) {
    int lo = base + t * 16;
    int v[16];
    int sum = 0;
#pragma unroll
    for (int j = 0; j < 16; ++j) {
      int i = lo + j;
      v[j] = (i < N_NODES) ? cnt[i] : 0;
      sum += v[j];
    }
    sums[t] = sum;
    __syncthreads();
    for (int ds = 1; ds < 256; ds <<= 1) {
      int add = (t >= ds) ? sums[t - ds] : 0;
      __syncthreads();
      sums[t] += add;
      __syncthreads();
    }
    int excl = carry + sums[t] - sum;
#pragma unroll
    for (int j = 0; j < 16; ++j) {
      int i = lo + j;
      if (i < N_NODES) offs[i] = excl;
      excl += v[j];
    }
    __syncthreads();
    if (t == 255) carry += sums[255];
    __syncthreads();
  }
}

__global__ void fill_kernel(const int* __restrict__ ei, const int* __restrict__ flags,
                            const int* __restrict__ offs, int* __restrict__ cursor,
                            int* __restrict__ adj, int E) {
  int e = blockIdx.x * blockDim.x + threadIdx.x;
  if (e >= E) return;
  int s, d;
  if (flags[1]) { s = ei[e]; d = ei[E + e]; }
  else          { s = ei[2 * e]; d = ei[2 * (E + e)]; }
  if ((u32)s >= N_NODES || (u32)d >= N_NODES) return;
  int pos = atomicAdd(&cursor[d], 1);
  adj[offs[d] + pos] = s;
}

__global__ void dinv_kernel(const int* __restrict__ cnt, float* __restrict__ dinv, int n) {
  int i = blockIdx.x * blockDim.x + threadIdx.x;
  if (i >= n) return;
  dinv[i] = rsqrtf((float)(cnt[i] + 1));  // deg = indeg + self-loop
}

// ---------------- VALU GEMM 1: hx = x @ W1 ----------------
// one block = 8 nodes; thread t owns output column t; intermediates bf16

template<class T>
__global__ __launch_bounds__(256) void valu_gemm1(const void* __restrict__ x,
                                                  const void* __restrict__ W1,
                                                  u16* __restrict__ hx,
                                                  const int* __restrict__ flags) {
  if (flags[0] != IsF32<T>::v) return;
  __shared__ float xs[8][IN_CH];
  int t = threadIdx.x;
  size_t base = (size_t)blockIdx.x * 8 * IN_CH;
  for (int i = t; i < 8 * IN_CH; i += 256)
    xs[i >> 9][i & 511] = ldv<T>(x, base + i);
  __syncthreads();
  float acc[8] = {};
  for (int k = 0; k < IN_CH; ++k) {
    float w = ldv<T>(W1, (size_t)k * HID_CH + t);  // coalesced over t
#pragma unroll
    for (int r = 0; r < 8; ++r) acc[r] += xs[r][k] * w;
  }
  size_t ob = (size_t)blockIdx.x * 8 * HID_CH + t;
#pragma unroll
  for (int r = 0; r < 8; ++r) hx[ob + (size_t)r * HID_CH] = f2b(acc[r]);
}

// ---------------- VALU GEMM 2: hml = h @ [Wmu | Wlv] ----------------

template<class T>
__global__ __launch_bounds__(256) void valu_gemm2(const u16* __restrict__ h,
                                                  const void* __restrict__ Wmu,
                                                  const void* __restrict__ Wlv,
                                                  u16* __restrict__ hml,
                                                  const int* __restrict__ flags) {
  if (flags[0] != IsF32<T>::v) return;
  __shared__ float hs[8][HID_CH];
  int t = threadIdx.x;
  size_t base = (size_t)blockIdx.x * 8 * HID_CH;
  for (int i = t; i < 8 * HID_CH; i += 256)
    hs[i >> 8][i & 255] = b2f(h[base + i]);
  __syncthreads();
  int col = t & 127;
  int rg = (t >> 7) * 4;
  const void* W = (col < 64) ? Wmu : Wlv;
  int wc = col & 63;
  float acc[4] = {};
  for (int k = 0; k < HID_CH; ++k) {
    float w = ldv<T>(W, (size_t)k * 64 + wc);
#pragma unroll
    for (int r = 0; r < 4; ++r) acc[r] += hs[rg + r][k] * w;
  }
  size_t ob = (size_t)blockIdx.x * 8 * 128 + col;
#pragma unroll
  for (int r = 0; r < 4; ++r) hml[ob + (size_t)(rg + r) * 128] = f2b(acc[r]);
}

// ---------------- aggregation 1 (256 ch) + bias + relu -> h ----------------

template<class T>
__global__ __launch_bounds__(256) void agg1_kernel(const u16* __restrict__ hx,
                                                   const int* __restrict__ cnt,
                                                   const int* __restrict__ offs,
                                                   const int* __restrict__ adj,
                                                   const float* __restrict__ dinv,
                                                   const void* __restrict__ b1,
                                                   u16* __restrict__ h,
                                                   const int* __restrict__ flags) {
  if (flags[0] != IsF32<T>::v) return;
  int d = blockIdx.x * 4 + (threadIdx.x >> 6);
  if (d >= N_NODES) return;
  int lane = threadIdx.x & 63;
  int c = lane * 4;
  float a0 = 0.f, a1 = 0.f, a2 = 0.f, a3 = 0.f;
  int n = cnt[d];
  float dv = dinv[d];
  const int* ent = adj + offs[d];
  for (int j = 0; j < n; ++j) {
    int s = ent[j];
    float w = dv * dinv[s];
    const u16* p = hx + (size_t)s * HID_CH + c;
    a0 += w * b2f(p[0]); a1 += w * b2f(p[1]);
    a2 += w * b2f(p[2]); a3 += w * b2f(p[3]);
  }
  {  // self loop
    float w = dv * dv;
    const u16* p = hx + (size_t)d * HID_CH + c;
    a0 += w * b2f(p[0]); a1 += w * b2f(p[1]);
    a2 += w * b2f(p[2]); a3 += w * b2f(p[3]);
  }
  a0 = fmaxf(a0 + ldv<T>(b1, c), 0.f);
  a1 = fmaxf(a1 + ldv<T>(b1, c + 1), 0.f);
  a2 = fmaxf(a2 + ldv<T>(b1, c + 2), 0.f);
  a3 = fmaxf(a3 + ldv<T>(b1, c + 3), 0.f);
  u16* q = h + (size_t)d * HID_CH + c;
  q[0] = f2b(a0); q[1] = f2b(a1); q[2] = f2b(a2); q[3] = f2b(a3);
}

// ---------------- aggregation 2 (128 ch) + bias + reparam ----------------

template<class T>
__global__ __launch_bounds__(256) void agg2_kernel(const u16* __restrict__ hml,
                                                   const int* __restrict__ cnt,
                                                   const int* __restrict__ offs,
                                                   const int* __restrict__ adj,
                                                   const float* __restrict__ dinv,
                                                   const void* __restrict__ bmu,
                                                   const void* __restrict__ blv,
                                                   const void* __restrict__ eps,
                                                   void* __restrict__ mu_out,
                                                   void* __restrict__ lv_out,
                                                   u16* __restrict__ z,
                                                   const int* __restrict__ flags) {
  if (flags[0] != IsF32<T>::v) return;
  int d = blockIdx.x * 4 + (threadIdx.x >> 6);
  if (d >= N_NODES) return;
  int lane = threadIdx.x & 63;
  float am = 0.f, al = 0.f;
  int n = cnt[d];
  float dv = dinv[d];
  const int* ent = adj + offs[d];
  for (int j = 0; j < n; ++j) {
    int s = ent[j];
    float w = dv * dinv[s];
    am += w * b2f(hml[(size_t)s * 128 + lane]);
    al += w * b2f(hml[(size_t)s * 128 + 64 + lane]);
  }
  {  // self loop
    float w = dv * dv;
    am += w * b2f(hml[(size_t)d * 128 + lane]);
    al += w * b2f(hml[(size_t)d * 128 + 64 + lane]);
  }
  am += ldv<T>(bmu, lane);
  al += ldv<T>(blv, lane);
  size_t o = (size_t)d * 64 + lane;
  stv<T>(mu_out, o, am);
  stv<T>(lv_out, o, al);
  float zz = am + ldv<T>(eps, o) * expf(0.5f * al);
  z[o] = f2b(zz);
}

// ---------------- final small GEMM: out = z @ Wc + bc ----------------

template<class T>
__global__ __launch_bounds__(256) void out_gemm(const u16* __restrict__ z,
                                                const void* __restrict__ Wc,
                                                const void* __restrict__ bc,
                                                void* __restrict__ out,
                                                const int* __restrict__ flags) {
  if (flags[0] != IsF32<T>::v) return;
  __shared__ float Wcs[64][65];
  __shared__ float zs[4][65];
  int t = threadIdx.x;
  for (int i = t; i < 4096; i += 256) Wcs[i >> 6][i & 63] = ldv<T>(Wc, i);
  int ln = t >> 6;
  int col = t & 63;
  int node = blockIdx.x * 4 + ln;
  zs[ln][col] = b2f(z[(size_t)node * 64 + col]);
  __syncthreads();
  float acc = ldv<T>(bc, col);
#pragma unroll
  for (int k = 0; k < 64; ++k) acc += zs[ln][k] * Wcs[k][col];
  stv<T>(out, (size_t)node * 64 + col, acc);
}

// ---------------- launch ----------------

extern "C" void kernel_launch(void* const* d_in, const int* in_sizes, int n_in,
                              void* d_out, int out_size, void* d_ws, size_t ws_size,
                              hipStream_t stream) {
  const void* x   = d_in[0];
  const int*  ei  = (const int*)d_in[1];
  const void* W1  = d_in[2];
  const void* b1  = d_in[3];
  const void* Wmu = d_in[4];
  const void* bmu = d_in[5];
  const void* Wlv = d_in[6];
  const void* blv = d_in[7];
  const void* Wc  = d_in[8];
  const void* bc  = d_in[9];
  const void* eps = d_in[10];
  int E = in_sizes[1] / 2;

  char* ws = (char*)d_ws;
  int*   flags  = (int*)(ws);                    // 64 B
  int*   cnt    = (int*)(ws + 1024);             // 400 KB
  int*   cursor = (int*)(ws + (512 << 10));      // 400 KB
  int*   offs   = (int*)(ws + (1 << 20));        // 400 KB
  float* dinv   = (float*)(ws + (1536 << 10));   // 400 KB
  int*   adj    = (int*)(ws + (2 << 20));        // 12.8 MB
  size_t hx_off = (2 << 20) + (size_t)CAP_E * 4;
  u16* hx  = (u16*)(ws + hx_off);                                  // 51.2 MB
  u16* h   = (u16*)(ws + hx_off + (size_t)N_NODES * HID_CH * 2);   // 51.2 MB
  u16* hml = hx;  // hx dead after agg1; reuse (25.6 MB)
  u16* z   = (u16*)(ws + hx_off + (size_t)N_NODES * 128 * 2);      // 12.8 MB

  hipMemsetAsync(ws, 0, 2 << 20, stream);

  detect_kernel<<<1, 256, 0, stream>>>((const u32*)x, ei, flags);
  count_kernel<<<(E + 255) / 256, 256, 0, stream>>>(ei, flags, cnt, E);
  scan_kernel<<<1, 256, 0, stream>>>(cnt, offs);
  fill_kernel<<<(E + 255) / 256, 256, 0, stream>>>(ei, flags, offs, cursor, adj, E);
  dinv_kernel<<<(N_NODES + 255) / 256, 256, 0, stream>>>(cnt, dinv, N_NODES);

  // hx = x @ W1
  valu_gemm1<TyBF ><<<N_NODES / 8, 256, 0, stream>>>(x, W1, hx, flags);
  valu_gemm1<TyF32><<<N_NODES / 8, 256, 0, stream>>>(x, W1, hx, flags);

  // h = relu(agg(hx) + b1)
  agg1_kernel<TyBF ><<<N_NODES / 4, 256, 0, stream>>>(hx, cnt, offs, adj, dinv, b1, h, flags);
  agg1_kernel<TyF32><<<N_NODES / 4, 256, 0, stream>>>(hx, cnt, offs, adj, dinv, b1, h, flags);

  // hml = h @ [Wmu | Wlv]
  valu_gemm2<TyBF ><<<N_NODES / 8, 256, 0, stream>>>(h, Wmu, Wlv, hml, flags);
  valu_gemm2<TyF32><<<N_NODES / 8, 256, 0, stream>>>(h, Wmu, Wlv, hml, flags);

  // mu, logvar, z  (outputs: [out | mu | logvar], each 100000*64)
  {
    char* ob = (char*)d_out;
    size_t esz_bf = 2, esz_f32 = 4;
    void* mu_bf  = ob + (size_t)N_NODES * 64 * esz_bf;
    void* lv_bf  = ob + (size_t)N_NODES * 128 * esz_bf;
    void* mu_f32 = ob + (size_t)N_NODES * 64 * esz_f32;
    void* lv_f32 = ob + (size_t)N_NODES * 128 * esz_f32;
    agg2_kernel<TyBF ><<<N_NODES / 4, 256, 0, stream>>>(hml, cnt, offs, adj, dinv, bmu, blv,
                                                        eps, mu_bf, lv_bf, z, flags);
    agg2_kernel<TyF32><<<N_NODES / 4, 256, 0, stream>>>(hml, cnt, offs, adj, dinv, bmu, blv,
                                                        eps, mu_f32, lv_f32, z, flags);
  }

  // out = z @ Wc + bc
  out_gemm<TyBF ><<<N_NODES / 4, 256, 0, stream>>>(z, Wc, bc, d_out, flags);
  out_gemm<TyF32><<<N_NODES / 4, 256, 0, stream>>>(z, Wc, bc, d_out, flags);
}